// Round 1
// baseline (1051.919 us; speedup 1.0000x reference)
//
#include <hip/hip_runtime.h>
#include <stdint.h>

typedef unsigned short u16;
typedef __bf16 bf16x8 __attribute__((ext_vector_type(8)));
typedef float f32x4 __attribute__((ext_vector_type(4)));

// ---- constants for this problem ----
// B=8, N=1024, C=768, H=12, HD=64, FF=2048, M = B*N = 8192
// out layout (f32): src[6291456] | scorenet[8000] | y[8000] | attn[100663296]

__device__ __forceinline__ u16 f2bf(float f) {
  union { float f; unsigned u; } v; v.f = f;
  unsigned r = v.u + 0x7fffu + ((v.u >> 16) & 1u);  // RNE
  return (u16)(r >> 16);
}

__device__ __forceinline__ void async16(const void* g, void* l) {
  __builtin_amdgcn_global_load_lds(
      (const __attribute__((address_space(1))) void*)g,
      (__attribute__((address_space(3))) void*)l, 16, 0, 0);
}

__device__ __forceinline__ f32x4 mfma16(bf16x8 a, bf16x8 b, f32x4 c) {
  return __builtin_amdgcn_mfma_f32_16x16x32_bf16(a, b, c, 0, 0, 0);
}

__device__ __forceinline__ float gelu_exact(float x) {
  return 0.5f * x * (1.0f + erff(x * 0.70710678118654752440f));
}

// ---------------- LayerNorm: f32 [8192,768] -> bf16 (+optional f32) --------
__global__ __launch_bounds__(256) void ln_kernel(
    const float* __restrict__ x, const float* __restrict__ g,
    const float* __restrict__ b, u16* __restrict__ obf,
    float* __restrict__ of) {
  const size_t row = blockIdx.x;
  const float* xr = x + row * 768;
  const int t = threadIdx.x;
  const int w = t >> 6, lane = t & 63;
  float v0 = xr[t], v1 = xr[t + 256], v2 = xr[t + 512];
  float s = v0 + v1 + v2;
  float sq = v0 * v0 + v1 * v1 + v2 * v2;
#pragma unroll
  for (int off = 32; off > 0; off >>= 1) {
    s += __shfl_down(s, off);
    sq += __shfl_down(sq, off);
  }
  __shared__ float ss[4], ssq[4];
  if (lane == 0) { ss[w] = s; ssq[w] = sq; }
  __syncthreads();
  s = ss[0] + ss[1] + ss[2] + ss[3];
  sq = ssq[0] + ssq[1] + ssq[2] + ssq[3];
  const float mean = s * (1.0f / 768.0f);
  const float var = sq * (1.0f / 768.0f) - mean * mean;
  const float rstd = rsqrtf(var + 1e-5f);
  float y0 = (v0 - mean) * rstd * g[t] + b[t];
  float y1 = (v1 - mean) * rstd * g[t + 256] + b[t + 256];
  float y2 = (v2 - mean) * rstd * g[t + 512] + b[t + 512];
  obf[row * 768 + t] = f2bf(y0);
  obf[row * 768 + t + 256] = f2bf(y1);
  obf[row * 768 + t + 512] = f2bf(y2);
  if (of) {
    of[row * 768 + t] = y0;
    of[row * 768 + t + 256] = y1;
    of[row * 768 + t + 512] = y2;
  }
}

// ------------- transpose + cvt: W f32 [K][N] -> Wt bf16 [N][K] --------------
__global__ void transpose_cvt_kernel(const float* __restrict__ W,
                                     u16* __restrict__ Wt, int K, int N) {
  __shared__ float tile[32][33];
  const int n0 = blockIdx.x * 32, k0 = blockIdx.y * 32;
  const int tx = threadIdx.x, ty = threadIdx.y;  // (32,8)
  for (int r = ty; r < 32; r += 8)
    tile[r][tx] = W[(size_t)(k0 + r) * N + n0 + tx];
  __syncthreads();
  for (int r = ty; r < 32; r += 8)
    Wt[(size_t)(n0 + r) * K + k0 + tx] = f2bf(tile[tx][r]);
}

// ------------- V transpose: qkv bf16 -> vt[bh][d][n] ------------------------
__global__ void vt_kernel(const u16* __restrict__ qkv, u16* __restrict__ vt) {
  // grid (1024/32, 64/32, 96), block (32,8)
  const int bh = blockIdx.z, b = bh / 12, h = bh % 12;
  const int n0 = blockIdx.x * 32, d0 = blockIdx.y * 32;
  __shared__ u16 tile[32][33];
  const u16* Vp = qkv + (size_t)b * 1024 * 2304 + 1536 + h * 64;
  const int tx = threadIdx.x, ty = threadIdx.y;
  for (int r = ty; r < 32; r += 8)
    tile[r][tx] = Vp[(size_t)(n0 + r) * 2304 + d0 + tx];
  __syncthreads();
  u16* Op = vt + (size_t)bh * 64 * 1024;
  for (int r = ty; r < 32; r += 8)
    Op[(size_t)(d0 + r) * 1024 + n0 + tx] = tile[tx][r];
}

// ------------- generic 128x128 bf16 MFMA GEMM (m97 structure) ---------------
// C[M,N] = A[M,K] @ Bt[N,K]^T ; optional bias/res/gelu; outF f32 / outB bf16
__global__ __launch_bounds__(256) void gemm128_kernel(
    const u16* __restrict__ A, int lda, const u16* __restrict__ Bt, int ldb,
    const float* __restrict__ bias, const float* __restrict__ res,
    float* __restrict__ outF, u16* __restrict__ outB, int ldc, int K,
    int act) {
  __shared__ u16 As[128 * 32];
  __shared__ u16 Bs[128 * 32];
  const int tid = threadIdx.x;
  const int w = tid >> 6, lane = tid & 63;
  const size_t mBase = (size_t)blockIdx.y * 128;
  const size_t nBase = (size_t)blockIdx.x * 128;
  const int rq = lane >> 2;       // 0..15: row within 16-row chunk
  const int k8 = (lane & 3) * 8;  // k-offset of this lane's 16B
  const int wr = w >> 1, wc = w & 1;
  const int tm = lane & 15, kq = lane >> 4;
  const f32x4 zero = {0.f, 0.f, 0.f, 0.f};
  f32x4 acc[4][4];
#pragma unroll
  for (int i = 0; i < 4; i++)
#pragma unroll
    for (int j = 0; j < 4; j++) acc[i][j] = zero;

  for (int kt = 0; kt < K; kt += 32) {
    __syncthreads();
#pragma unroll
    for (int q = 0; q < 2; ++q) {
      const int r0 = w * 32 + q * 16;  // wave-uniform 16-row chunk
      async16(A + (mBase + r0 + rq) * lda + kt + k8, &As[r0 * 32]);
      async16(Bt + (nBase + r0 + rq) * ldb + kt + k8, &Bs[r0 * 32]);
    }
    __syncthreads();  // compiler drains vmcnt before s_barrier
    bf16x8 af[4], bfv[4];
#pragma unroll
    for (int i = 0; i < 4; i++)
      af[i] = *(const bf16x8*)&As[(wr * 64 + i * 16 + tm) * 32 + kq * 8];
#pragma unroll
    for (int j = 0; j < 4; j++)
      bfv[j] = *(const bf16x8*)&Bs[(wc * 64 + j * 16 + tm) * 32 + kq * 8];
#pragma unroll
    for (int i = 0; i < 4; i++)
#pragma unroll
      for (int j = 0; j < 4; j++) acc[i][j] = mfma16(af[i], bfv[j], acc[i][j]);
  }

#pragma unroll
  for (int i = 0; i < 4; i++) {
    const size_t row0 = mBase + wr * 64 + i * 16 + kq * 4;
#pragma unroll
    for (int j = 0; j < 4; j++) {
      const size_t col = nBase + wc * 64 + j * 16 + tm;
      const float bv = bias ? bias[col] : 0.0f;
#pragma unroll
      for (int r = 0; r < 4; r++) {
        const size_t rr = row0 + r;
        float v = acc[i][j][r] + bv;
        if (act) v = gelu_exact(v);
        if (res) v += res[rr * ldc + col];
        if (outF) outF[rr * ldc + col] = v;
        if (outB) outB[rr * ldc + col] = f2bf(v);
      }
    }
  }
}

// ------------- attention scores: S = Q K^T * 0.125, batched over 96 --------
__global__ __launch_bounds__(256) void attn_scores_kernel(
    const u16* __restrict__ qkv, float* __restrict__ attn) {
  __shared__ u16 As[128 * 32];
  __shared__ u16 Bs[128 * 32];
  const int tid = threadIdx.x;
  const int w = tid >> 6, lane = tid & 63;
  const int bh = blockIdx.z, b = bh / 12, h = bh % 12;
  const size_t mBase = (size_t)blockIdx.y * 128;
  const size_t nBase = (size_t)blockIdx.x * 128;
  const u16* Qp = qkv + (size_t)b * 1024 * 2304 + h * 64;
  const u16* Kp = Qp + 768;
  const int rq = lane >> 2, k8 = (lane & 3) * 8;
  const int wr = w >> 1, wc = w & 1;
  const int tm = lane & 15, kq = lane >> 4;
  const f32x4 zero = {0.f, 0.f, 0.f, 0.f};
  f32x4 acc[4][4];
#pragma unroll
  for (int i = 0; i < 4; i++)
#pragma unroll
    for (int j = 0; j < 4; j++) acc[i][j] = zero;

#pragma unroll
  for (int kt = 0; kt < 64; kt += 32) {
    __syncthreads();
#pragma unroll
    for (int q = 0; q < 2; ++q) {
      const int r0 = w * 32 + q * 16;
      async16(Qp + (mBase + r0 + rq) * 2304 + kt + k8, &As[r0 * 32]);
      async16(Kp + (nBase + r0 + rq) * 2304 + kt + k8, &Bs[r0 * 32]);
    }
    __syncthreads();
    bf16x8 af[4], bfv[4];
#pragma unroll
    for (int i = 0; i < 4; i++)
      af[i] = *(const bf16x8*)&As[(wr * 64 + i * 16 + tm) * 32 + kq * 8];
#pragma unroll
    for (int j = 0; j < 4; j++)
      bfv[j] = *(const bf16x8*)&Bs[(wc * 64 + j * 16 + tm) * 32 + kq * 8];
#pragma unroll
    for (int i = 0; i < 4; i++)
#pragma unroll
      for (int j = 0; j < 4; j++) acc[i][j] = mfma16(af[i], bfv[j], acc[i][j]);
  }

  float* Cb = attn + (size_t)bh * 1024 * 1024;
#pragma unroll
  for (int i = 0; i < 4; i++) {
    const size_t row0 = mBase + wr * 64 + i * 16 + kq * 4;
#pragma unroll
    for (int j = 0; j < 4; j++) {
      const size_t col = nBase + wc * 64 + j * 16 + tm;
#pragma unroll
      for (int r = 0; r < 4; r++)
        Cb[(row0 + r) * 1024 + col] = acc[i][j][r] * 0.125f;
    }
  }
}

// ------------- softmax in place over rows of 1024 ---------------------------
__global__ __launch_bounds__(256) void softmax_kernel(float* __restrict__ p) {
  const size_t row = blockIdx.x;
  float* pr = p + row * 1024;
  const int t = threadIdx.x, w = t >> 6, lane = t & 63;
  float4 v = ((const float4*)pr)[t];
  float m = fmaxf(fmaxf(v.x, v.y), fmaxf(v.z, v.w));
#pragma unroll
  for (int off = 32; off > 0; off >>= 1) m = fmaxf(m, __shfl_xor(m, off));
  __shared__ float sr1[4], sr2[4];
  if (lane == 0) sr1[w] = m;
  __syncthreads();
  m = fmaxf(fmaxf(sr1[0], sr1[1]), fmaxf(sr1[2], sr1[3]));
  v.x = expf(v.x - m); v.y = expf(v.y - m);
  v.z = expf(v.z - m); v.w = expf(v.w - m);
  float s = v.x + v.y + v.z + v.w;
#pragma unroll
  for (int off = 32; off > 0; off >>= 1) s += __shfl_xor(s, off);
  if (lane == 0) sr2[w] = s;
  __syncthreads();
  s = sr2[0] + sr2[1] + sr2[2] + sr2[3];
  const float inv = 1.0f / s;
  v.x *= inv; v.y *= inv; v.z *= inv; v.w *= inv;
  ((float4*)pr)[t] = v;
}

// ------------- AV: O = P[1024,1024] @ V[1024,64]  (Vt pre-transposed) -------
__global__ __launch_bounds__(256) void attn_av_kernel(
    const float* __restrict__ attn, const u16* __restrict__ vt,
    u16* __restrict__ aout) {
  __shared__ u16 As[128 * 32];
  __shared__ u16 Bs[64 * 32];
  const int tid = threadIdx.x;
  const int w = tid >> 6, lane = tid & 63;
  const int bh = blockIdx.y, b = bh / 12, h = bh % 12;
  const size_t mBase = (size_t)blockIdx.x * 128;
  const float* Ap = attn + (size_t)bh * 1024 * 1024;
  const u16* Bp = vt + (size_t)bh * 64 * 1024;
  const int rq = lane >> 2, k8 = (lane & 3) * 8;
  const int tm = lane & 15, kq = lane >> 4;
  const f32x4 zero = {0.f, 0.f, 0.f, 0.f};
  f32x4 acc[2][4];
#pragma unroll
  for (int i = 0; i < 2; i++)
#pragma unroll
    for (int j = 0; j < 4; j++) acc[i][j] = zero;

  for (int kt = 0; kt < 1024; kt += 32) {
    __syncthreads();
    // B tile (Vt rows = d, contiguous k): 64x32 bf16 via global_load_lds
    async16(Bp + (size_t)(w * 16 + rq) * 1024 + kt + k8, &Bs[w * 16 * 32]);
    // A tile: f32 attn -> bf16 LDS, 128x32
#pragma unroll
    for (int it = 0; it < 4; ++it) {
      const int r = it * 32 + (tid >> 3);
      const int q = tid & 7;
      const float4 v = *(const float4*)&Ap[(mBase + r) * 1024 + kt + q * 4];
      uint2 pk;
      pk.x = (unsigned)f2bf(v.x) | ((unsigned)f2bf(v.y) << 16);
      pk.y = (unsigned)f2bf(v.z) | ((unsigned)f2bf(v.w) << 16);
      *(uint2*)&As[r * 32 + q * 4] = pk;
    }
    __syncthreads();
    bf16x8 af[2], bfv[4];
#pragma unroll
    for (int i = 0; i < 2; i++)
      af[i] = *(const bf16x8*)&As[(w * 32 + i * 16 + tm) * 32 + kq * 8];
#pragma unroll
    for (int j = 0; j < 4; j++)
      bfv[j] = *(const bf16x8*)&Bs[(j * 16 + tm) * 32 + kq * 8];
#pragma unroll
    for (int i = 0; i < 2; i++)
#pragma unroll
      for (int j = 0; j < 4; j++) acc[i][j] = mfma16(af[i], bfv[j], acc[i][j]);
  }

  const size_t bOff = (size_t)b * 1024;
#pragma unroll
  for (int i = 0; i < 2; i++) {
#pragma unroll
    for (int j = 0; j < 4; j++) {
      const int d = j * 16 + tm;
#pragma unroll
      for (int r = 0; r < 4; r++) {
        const size_t m = mBase + w * 32 + i * 16 + kq * 4 + r;
        aout[(bOff + m) * 768 + h * 64 + d] = f2bf(acc[i][j][r]);
      }
    }
  }
}

// ------------- passthrough copies ------------------------------------------
__global__ void copy_misc_kernel(const float* __restrict__ y,
                                 const float* __restrict__ sc,
                                 float* __restrict__ out) {
  const int i = blockIdx.x * 256 + threadIdx.x;
  if (i < 8000) {
    out[6291456 + i] = sc[i];  // scorenet_h_src
    out[6299456 + i] = y[i];   // y
  }
}

extern "C" void kernel_launch(void* const* d_in, const int* in_sizes, int n_in,
                              void* d_out, int out_size, void* d_ws,
                              size_t ws_size, hipStream_t stream) {
  const float* src    = (const float*)d_in[0];
  const float* yin    = (const float*)d_in[1];
  const float* scin   = (const float*)d_in[2];
  const float* pre_g  = (const float*)d_in[3];
  const float* pre_b  = (const float*)d_in[4];
  const float* qkv_w  = (const float*)d_in[5];
  const float* proj_w = (const float*)d_in[6];
  const float* proj_b = (const float*)d_in[7];
  const float* n1_g   = (const float*)d_in[8];
  const float* n1_b   = (const float*)d_in[9];
  const float* l1_w   = (const float*)d_in[10];
  const float* l1_b   = (const float*)d_in[11];
  const float* l2_w   = (const float*)d_in[12];
  const float* l2_b   = (const float*)d_in[13];
  float* outp = (float*)d_out;
  float* attn = outp + 6307456;  // src(6291456) + sc(8000) + y(8000)

  char* ws = (char*)d_ws;
  // persistent transposed bf16 weights
  u16* qkvwT  = (u16*)(ws + 0ull);          // 2304x768
  u16* projwT = (u16*)(ws + 3538944ull);    // 768x768
  u16* l1wT   = (u16*)(ws + 4718592ull);    // 2048x768
  u16* l2wT   = (u16*)(ws + 7864320ull);    // 768x2048
  const size_t P0 = 11010048ull;
  // phase A (attention)
  u16* xn   = (u16*)(ws + P0);                 // 8192x768 bf16
  u16* qkv  = (u16*)(ws + P0 + 12582912ull);   // 8192x2304 bf16
  u16* vt   = (u16*)(ws + P0 + 50331648ull);   // 96x64x1024 bf16
  u16* aout = (u16*)(ws + P0 + 62914560ull);   // 8192x768 bf16
  // phase B (MLP) — overlaps freed phase-A buffers (lifetimes checked)
  float* src2 = (float*)(ws + P0);                // 8192x768 f32
  u16*  snb   = (u16*)(ws + P0 + 25165824ull);    // 8192x768 bf16
  u16*  hbuf  = (u16*)(ws + P0 + 37748736ull);    // 8192x2048 bf16
  float* snf  = (float*)(ws + P0 + 71303168ull);  // 8192x768 f32

  dim3 tb(32, 8);
  // weights -> bf16 transposed
  transpose_cvt_kernel<<<dim3(72, 24), tb, 0, stream>>>(qkv_w, qkvwT, 768, 2304);
  transpose_cvt_kernel<<<dim3(24, 24), tb, 0, stream>>>(proj_w, projwT, 768, 768);
  transpose_cvt_kernel<<<dim3(64, 24), tb, 0, stream>>>(l1_w, l1wT, 768, 2048);
  transpose_cvt_kernel<<<dim3(24, 64), tb, 0, stream>>>(l2_w, l2wT, 2048, 768);
  // pre-LN
  ln_kernel<<<8192, 256, 0, stream>>>(src, pre_g, pre_b, xn, nullptr);
  // QKV gemm: [8192,768]@[768,2304] -> bf16
  gemm128_kernel<<<dim3(18, 64), 256, 0, stream>>>(
      xn, 768, qkvwT, 768, nullptr, nullptr, nullptr, qkv, 2304, 768, 0);
  // V transpose per head
  vt_kernel<<<dim3(32, 2, 96), tb, 0, stream>>>(qkv, vt);
  // scores + softmax + AV
  attn_scores_kernel<<<dim3(8, 8, 96), 256, 0, stream>>>(qkv, attn);
  softmax_kernel<<<98304, 256, 0, stream>>>(attn);
  attn_av_kernel<<<dim3(8, 96), 256, 0, stream>>>(attn, vt, aout);
  // proj + residual(src) -> src2 f32
  gemm128_kernel<<<dim3(6, 64), 256, 0, stream>>>(
      aout, 768, projwT, 768, proj_b, src, src2, nullptr, 768, 768, 0);
  // LN2 -> bf16 + f32
  ln_kernel<<<8192, 256, 0, stream>>>(src2, n1_g, n1_b, snb, snf);
  // FFN1 with exact GELU -> bf16
  gemm128_kernel<<<dim3(16, 64), 256, 0, stream>>>(
      snb, 768, l1wT, 768, l1_b, nullptr, nullptr, hbuf, 2048, 768, 1);
  // FFN2 + residual(src_n) -> d_out src region
  gemm128_kernel<<<dim3(6, 64), 256, 0, stream>>>(
      hbuf, 2048, l2wT, 2048, l2_b, snf, outp, nullptr, 768, 2048, 0);
  // passthrough outputs
  copy_misc_kernel<<<32, 256, 0, stream>>>(yin, scin, outp);
}

// Round 2
// 935.713 us; speedup vs baseline: 1.1242x; 1.1242x over previous
//
#include <hip/hip_runtime.h>
#include <stdint.h>

typedef unsigned short u16;
typedef __bf16 bf16x8 __attribute__((ext_vector_type(8)));
typedef float f32x4 __attribute__((ext_vector_type(4)));

// B=8, N=1024, C=768, H=12, HD=64, FF=2048, M=8192
// out (f32): src[6291456] | scorenet[8000] | y[8000] | attn[100663296]

__device__ __forceinline__ u16 f2bf(float f) {
  union { float f; unsigned u; } v; v.f = f;
  unsigned r = v.u + 0x7fffu + ((v.u >> 16) & 1u);  // RNE
  return (u16)(r >> 16);
}
__device__ __forceinline__ float bf2f(unsigned u) {
  union { unsigned u; float f; } v; v.u = u << 16; return v.f;
}

__device__ __forceinline__ void async16(const void* g, void* l) {
  __builtin_amdgcn_global_load_lds(
      (const __attribute__((address_space(1))) void*)g,
      (__attribute__((address_space(3))) void*)l, 16, 0, 0);
}

__device__ __forceinline__ f32x4 mfma16(bf16x8 a, bf16x8 b, f32x4 c) {
  return __builtin_amdgcn_mfma_f32_16x16x32_bf16(a, b, c, 0, 0, 0);
}

__device__ __forceinline__ float gelu_exact(float x) {
  return 0.5f * x * (1.0f + erff(x * 0.70710678118654752440f));
}

// ---------------- LayerNorm: f32 [8192,768] -> bf16 (+optional f32) --------
__global__ __launch_bounds__(256) void ln_kernel(
    const float* __restrict__ x, const float* __restrict__ g,
    const float* __restrict__ b, u16* __restrict__ obf,
    float* __restrict__ of) {
  const size_t row = blockIdx.x;
  const float* xr = x + row * 768;
  const int t = threadIdx.x;
  const int w = t >> 6, lane = t & 63;
  float v0 = xr[t], v1 = xr[t + 256], v2 = xr[t + 512];
  float s = v0 + v1 + v2;
  float sq = v0 * v0 + v1 * v1 + v2 * v2;
#pragma unroll
  for (int off = 32; off > 0; off >>= 1) {
    s += __shfl_down(s, off);
    sq += __shfl_down(sq, off);
  }
  __shared__ float ss[4], ssq[4];
  if (lane == 0) { ss[w] = s; ssq[w] = sq; }
  __syncthreads();
  s = ss[0] + ss[1] + ss[2] + ss[3];
  sq = ssq[0] + ssq[1] + ssq[2] + ssq[3];
  const float mean = s * (1.0f / 768.0f);
  const float var = sq * (1.0f / 768.0f) - mean * mean;
  const float rstd = rsqrtf(var + 1e-5f);
  float y0 = (v0 - mean) * rstd * g[t] + b[t];
  float y1 = (v1 - mean) * rstd * g[t + 256] + b[t + 256];
  float y2 = (v2 - mean) * rstd * g[t + 512] + b[t + 512];
  obf[row * 768 + t] = f2bf(y0);
  obf[row * 768 + t + 256] = f2bf(y1);
  obf[row * 768 + t + 512] = f2bf(y2);
  if (of) {
    of[row * 768 + t] = y0;
    of[row * 768 + t + 256] = y1;
    of[row * 768 + t + 512] = y2;
  }
}

// ---- merged: 4 weight transposes (f32 [K][N] -> bf16 [N][K]) + copies -----
__device__ __forceinline__ void transpose_tile(float (*tile)[33],
                                               const float* __restrict__ W,
                                               u16* __restrict__ Wt, int K,
                                               int N, int bx, int by) {
  const int n0 = bx * 32, k0 = by * 32;
  const int tx = threadIdx.x, ty = threadIdx.y;  // (32,8)
  for (int r = ty; r < 32; r += 8)
    tile[r][tx] = W[(size_t)(k0 + r) * N + n0 + tx];
  __syncthreads();
  for (int r = ty; r < 32; r += 8)
    Wt[(size_t)(n0 + r) * K + k0 + tx] = f2bf(tile[tx][r]);
}

__global__ void misc_kernel(const float* __restrict__ qkv_w,
                            const float* __restrict__ proj_w,
                            const float* __restrict__ l1_w,
                            const float* __restrict__ l2_w,
                            u16* __restrict__ qkvwT, u16* __restrict__ projwT,
                            u16* __restrict__ l1wT, u16* __restrict__ l2wT,
                            const float* __restrict__ y,
                            const float* __restrict__ sc,
                            float* __restrict__ out) {
  __shared__ float tile[32][33];
  int bid = blockIdx.x;
  if (bid < 1728) { transpose_tile(tile, qkv_w, qkvwT, 768, 2304, bid % 72, bid / 72); return; }
  bid -= 1728;
  if (bid < 576) { transpose_tile(tile, proj_w, projwT, 768, 768, bid % 24, bid / 24); return; }
  bid -= 576;
  if (bid < 1536) { transpose_tile(tile, l1_w, l1wT, 768, 2048, bid % 64, bid / 64); return; }
  bid -= 1536;
  if (bid < 1536) { transpose_tile(tile, l2_w, l2wT, 2048, 768, bid % 24, bid / 24); return; }
  bid -= 1536;
  const int t = threadIdx.y * 32 + threadIdx.x;
  const int i = bid * 256 + t;
  if (i < 8000) {
    out[6291456 + i] = sc[i];
    out[6299456 + i] = y[i];
  }
}

// ------------- V transpose: qkv bf16 -> vt[bh][d][n] ------------------------
__global__ void vt_kernel(const u16* __restrict__ qkv, u16* __restrict__ vt) {
  // grid (32, 2, 96), block (32,8)
  const int bh = blockIdx.z, b = bh / 12, h = bh % 12;
  const int n0 = blockIdx.x * 32, d0 = blockIdx.y * 32;
  __shared__ u16 tile[32][33];
  const u16* Vp = qkv + (size_t)b * 1024 * 2304 + 1536 + h * 64;
  const int tx = threadIdx.x, ty = threadIdx.y;
  for (int r = ty; r < 32; r += 8)
    tile[r][tx] = Vp[(size_t)(n0 + r) * 2304 + d0 + tx];
  __syncthreads();
  u16* Op = vt + (size_t)bh * 64 * 1024;
  for (int r = ty; r < 32; r += 8)
    Op[(size_t)(d0 + r) * 1024 + n0 + tx] = tile[tx][r];
}

// ------------- templated bf16 MFMA GEMM --------------------------------------
// C[M,N] = A[M,K] @ Bt[N,K]^T ; wave grid GMxGN (GM*GN=4), per-wave WMxWN m16/n16
template <int BM, int BN, int GN, int WM, int WN>
__global__ __launch_bounds__(256) void gemm_kernel(
    const u16* __restrict__ A, int lda, const u16* __restrict__ Bt, int ldb,
    const float* __restrict__ bias, const float* __restrict__ res,
    float* __restrict__ outF, u16* __restrict__ outB, int ldc, int K,
    int act) {
  __shared__ u16 As[BM * 32];
  __shared__ u16 Bs[BN * 32];
  const int tid = threadIdx.x;
  const int w = tid >> 6, lane = tid & 63;
  const size_t mBase = (size_t)blockIdx.y * BM;
  const size_t nBase = (size_t)blockIdx.x * BN;
  const int rq = lane >> 2;       // row within 16-row chunk
  const int k8 = (lane & 3) * 8;  // k-offset of this lane's 16B
  const int wmBase = (w / GN) * (WM * 16);
  const int wnBase = (w % GN) * (WN * 16);
  const int tm = lane & 15, kq = lane >> 4;
  const f32x4 zero = {0.f, 0.f, 0.f, 0.f};
  f32x4 acc[WM][WN];
#pragma unroll
  for (int i = 0; i < WM; i++)
#pragma unroll
    for (int j = 0; j < WN; j++) acc[i][j] = zero;

  for (int kt = 0; kt < K; kt += 32) {
    __syncthreads();
#pragma unroll
    for (int c = w; c < BM / 16; c += 4)
      async16(A + (mBase + c * 16 + rq) * lda + kt + k8, &As[c * 16 * 32]);
#pragma unroll
    for (int c = w; c < BN / 16; c += 4)
      async16(Bt + (nBase + c * 16 + rq) * ldb + kt + k8, &Bs[c * 16 * 32]);
    __syncthreads();
    bf16x8 af[WM], bfv[WN];
#pragma unroll
    for (int i = 0; i < WM; i++)
      af[i] = *(const bf16x8*)&As[(wmBase + i * 16 + tm) * 32 + kq * 8];
#pragma unroll
    for (int j = 0; j < WN; j++)
      bfv[j] = *(const bf16x8*)&Bs[(wnBase + j * 16 + tm) * 32 + kq * 8];
#pragma unroll
    for (int i = 0; i < WM; i++)
#pragma unroll
      for (int j = 0; j < WN; j++) acc[i][j] = mfma16(af[i], bfv[j], acc[i][j]);
  }

#pragma unroll
  for (int i = 0; i < WM; i++) {
    const size_t row0 = mBase + wmBase + i * 16 + kq * 4;
#pragma unroll
    for (int j = 0; j < WN; j++) {
      const size_t col = nBase + wnBase + j * 16 + tm;
      const float bv = bias ? bias[col] : 0.0f;
#pragma unroll
      for (int r = 0; r < 4; r++) {
        const size_t rr = row0 + r;
        float v = acc[i][j][r] + bv;
        if (act) v = gelu_exact(v);
        if (res) v += res[rr * ldc + col];
        if (outF) outF[rr * ldc + col] = v;
        if (outB) outB[rr * ldc + col] = f2bf(v);
      }
    }
  }
}

// ------------- fused flash attention ----------------------------------------
// per block: (bh, 16-row Q strip). S=Q K^T*scale -> exp -> LDS bf16;
// row sums; write normalized attn f32 once; O = Ptilde @ V * inv.
__global__ __launch_bounds__(256) void flash_kernel(
    const u16* __restrict__ qkv, const u16* __restrict__ vt,
    float* __restrict__ attn, u16* __restrict__ aout) {
  __shared__ u16 Pt[16][1032];   // exp(S) bf16, padded (+8)
  __shared__ u16 Ks[128][68];    // K tile: 128 n x 64 k, padded
  __shared__ u16 Qs[16][68];     // Q strip: 16 m x 64 k, padded
  __shared__ u16 Vs[64][66];     // V tile: 64 d x 64 k(seq), padded
  __shared__ float rinv[16];
  const int tid = threadIdx.x;
  const int w = tid >> 6, lane = tid & 63;
  const int tm = lane & 15, kq = lane >> 4;
  const int bh = blockIdx.y, b = bh / 12, h = bh % 12;
  const size_t m0 = (size_t)blockIdx.x * 16;
  const u16* Qp = qkv + (size_t)b * 1024 * 2304 + h * 64;
  const u16* Kp = Qp + 768;
  const u16* Vp = vt + (size_t)bh * 64 * 1024;
  float* Ab = attn + (size_t)bh * 1024 * 1024 + m0 * 1024;

  // load Q strip (16 x 64)
  if (tid < 128) {
    const int r = tid >> 3, kc = tid & 7;
    *(uint4*)&Qs[r][kc * 8] = *(const uint4*)(Qp + (m0 + r) * 2304 + kc * 8);
  }

  // ---- S phase: chunks of 128 cols ----
  for (int nc = 0; nc < 1024; nc += 128) {
    __syncthreads();  // Ks reuse + (first iter) Qs ready
#pragma unroll
    for (int u = 0; u < 4; ++u) {
      const int idx = u * 256 + tid;
      const int r = idx >> 3, kc = idx & 7;
      *(uint4*)&Ks[r][kc * 8] =
          *(const uint4*)(Kp + (size_t)(nc + r) * 2304 + kc * 8);
    }
    __syncthreads();
    const bf16x8 aq0 = *(const bf16x8*)&Qs[tm][kq * 8];
    const bf16x8 aq1 = *(const bf16x8*)&Qs[tm][32 + kq * 8];
    const int n0 = w * 32;
    const bf16x8 b00 = *(const bf16x8*)&Ks[n0 + tm][kq * 8];
    const bf16x8 b01 = *(const bf16x8*)&Ks[n0 + tm][32 + kq * 8];
    const bf16x8 b10 = *(const bf16x8*)&Ks[n0 + 16 + tm][kq * 8];
    const bf16x8 b11 = *(const bf16x8*)&Ks[n0 + 16 + tm][32 + kq * 8];
    f32x4 acc0 = {0.f, 0.f, 0.f, 0.f}, acc1 = {0.f, 0.f, 0.f, 0.f};
    acc0 = mfma16(aq0, b00, acc0);
    acc0 = mfma16(aq1, b01, acc0);
    acc1 = mfma16(aq0, b10, acc1);
    acc1 = mfma16(aq1, b11, acc1);
#pragma unroll
    for (int r = 0; r < 4; ++r) {
      const int row = kq * 4 + r;
      // no max-subtraction: |s| <= ~4 here, exp is safe in f32
      Pt[row][nc + n0 + tm] = f2bf(__expf(acc0[r] * 0.125f));
      Pt[row][nc + n0 + 16 + tm] = f2bf(__expf(acc1[r] * 0.125f));
    }
  }
  __syncthreads();  // Pt complete

  // ---- row sums -> rinv ----
#pragma unroll
  for (int rr = 0; rr < 4; ++rr) {
    const int row = w * 4 + rr;
    float s = 0.f;
#pragma unroll
    for (int c = 0; c < 4; ++c) {
      const uint2 pk = *(const uint2*)&Pt[row][(c * 64 + lane) * 4];
      s += bf2f(pk.x & 0xffffu) + bf2f(pk.x >> 16) + bf2f(pk.y & 0xffffu) +
           bf2f(pk.y >> 16);
    }
#pragma unroll
    for (int off = 32; off > 0; off >>= 1) s += __shfl_xor(s, off);
    if (lane == 0) rinv[row] = 1.0f / s;
  }
  __syncthreads();  // rinv ready

  // ---- write normalized attn (the only write of the 402MB tensor) ----
#pragma unroll
  for (int rr = 0; rr < 4; ++rr) {
    const int row = w * 4 + rr;
    const float inv = rinv[row];
#pragma unroll
    for (int c = 0; c < 4; ++c) {
      const int col = (c * 64 + lane) * 4;
      const uint2 pk = *(const uint2*)&Pt[row][col];
      float4 o;
      o.x = bf2f(pk.x & 0xffffu) * inv;
      o.y = bf2f(pk.x >> 16) * inv;
      o.z = bf2f(pk.y & 0xffffu) * inv;
      o.w = bf2f(pk.y >> 16) * inv;
      *(float4*)&Ab[(size_t)row * 1024 + col] = o;
    }
  }

  // ---- AV phase: O[16 x 64] = Ptilde @ V, wave w owns d-tile w ----
  f32x4 oacc = {0.f, 0.f, 0.f, 0.f};
  for (int kt = 0; kt < 1024; kt += 64) {
    __syncthreads();  // Vs reuse
    {
      const int d = tid >> 2, kc = (tid & 3) * 8;
      *(uint4*)&Vs[d][kc] = *(const uint4*)(Vp + (size_t)d * 1024 + kt + kc);
      *(uint4*)&Vs[d][32 + kc] =
          *(const uint4*)(Vp + (size_t)d * 1024 + kt + 32 + kc);
    }
    __syncthreads();
    const bf16x8 ap0 = *(const bf16x8*)&Pt[tm][kt + kq * 8];
    const bf16x8 ap1 = *(const bf16x8*)&Pt[tm][kt + 32 + kq * 8];
    const bf16x8 bv0 = *(const bf16x8*)&Vs[w * 16 + tm][kq * 8];
    const bf16x8 bv1 = *(const bf16x8*)&Vs[w * 16 + tm][32 + kq * 8];
    oacc = mfma16(ap0, bv0, oacc);
    oacc = mfma16(ap1, bv1, oacc);
  }

  const size_t orow0 = (size_t)b * 1024 + m0;
#pragma unroll
  for (int r = 0; r < 4; ++r) {
    const int m = kq * 4 + r;
    aout[(orow0 + m) * 768 + h * 64 + w * 16 + tm] = f2bf(oacc[r] * rinv[m]);
  }
}

extern "C" void kernel_launch(void* const* d_in, const int* in_sizes, int n_in,
                              void* d_out, int out_size, void* d_ws,
                              size_t ws_size, hipStream_t stream) {
  const float* src    = (const float*)d_in[0];
  const float* yin    = (const float*)d_in[1];
  const float* scin   = (const float*)d_in[2];
  const float* pre_g  = (const float*)d_in[3];
  const float* pre_b  = (const float*)d_in[4];
  const float* qkv_w  = (const float*)d_in[5];
  const float* proj_w = (const float*)d_in[6];
  const float* proj_b = (const float*)d_in[7];
  const float* n1_g   = (const float*)d_in[8];
  const float* n1_b   = (const float*)d_in[9];
  const float* l1_w   = (const float*)d_in[10];
  const float* l1_b   = (const float*)d_in[11];
  const float* l2_w   = (const float*)d_in[12];
  const float* l2_b   = (const float*)d_in[13];
  float* outp = (float*)d_out;
  float* attn = outp + 6307456;

  char* ws = (char*)d_ws;
  u16* qkvwT  = (u16*)(ws + 0ull);          // 2304x768
  u16* projwT = (u16*)(ws + 3538944ull);    // 768x768
  u16* l1wT   = (u16*)(ws + 4718592ull);    // 2048x768
  u16* l2wT   = (u16*)(ws + 7864320ull);    // 768x2048
  const size_t P0 = 11010048ull;
  u16* xn   = (u16*)(ws + P0);                 // 8192x768 bf16
  u16* qkv  = (u16*)(ws + P0 + 12582912ull);   // 8192x2304 bf16
  u16* vt   = (u16*)(ws + P0 + 50331648ull);   // 96x64x1024 bf16
  u16* aout = (u16*)(ws + P0 + 62914560ull);   // 8192x768 bf16
  float* src2 = (float*)(ws + P0);                // 8192x768 f32 (over xn/qkv head)
  u16*  snb   = (u16*)(ws + P0 + 25165824ull);    // 8192x768 bf16
  u16*  hbuf  = (u16*)(ws + P0 + 37748736ull);    // 8192x2048 bf16
  float* snf  = (float*)(ws + P0 + 71303168ull);  // 8192x768 f32

  dim3 tb(32, 8);
  misc_kernel<<<5439, tb, 0, stream>>>(qkv_w, proj_w, l1_w, l2_w, qkvwT,
                                       projwT, l1wT, l2wT, yin, scin, outp);
  ln_kernel<<<8192, 256, 0, stream>>>(src, pre_g, pre_b, xn, nullptr);
  // QKV: [8192,768]@[768,2304] -> bf16
  gemm_kernel<128, 128, 2, 4, 4><<<dim3(18, 64), 256, 0, stream>>>(
      xn, 768, qkvwT, 768, nullptr, nullptr, nullptr, qkv, 2304, 768, 0);
  vt_kernel<<<dim3(32, 2, 96), tb, 0, stream>>>(qkv, vt);
  // fused scores+softmax+AV (writes attn f32 once, aout bf16)
  flash_kernel<<<dim3(64, 96), 256, 0, stream>>>(qkv, vt, attn, aout);
  // proj + residual(src) -> src2 f32 (64x128 tiles for grid balance)
  gemm_kernel<64, 128, 4, 4, 2><<<dim3(6, 128), 256, 0, stream>>>(
      aout, 768, projwT, 768, proj_b, src, src2, nullptr, 768, 768, 0);
  ln_kernel<<<8192, 256, 0, stream>>>(src2, n1_g, n1_b, snb, snf);
  // FFN1 + exact GELU -> bf16
  gemm_kernel<128, 128, 2, 4, 4><<<dim3(16, 64), 256, 0, stream>>>(
      snb, 768, l1wT, 768, l1_b, nullptr, nullptr, hbuf, 2048, 768, 1);
  // FFN2 + residual(src_n) -> out
  gemm_kernel<64, 128, 4, 4, 2><<<dim3(6, 128), 256, 0, stream>>>(
      hbuf, 2048, l2wT, 2048, l2_b, snf, outp, nullptr, 768, 2048, 0);
}

// Round 3
// 819.389 us; speedup vs baseline: 1.2838x; 1.1420x over previous
//
#include <hip/hip_runtime.h>
#include <stdint.h>

typedef unsigned short u16;
typedef __bf16 bf16x8 __attribute__((ext_vector_type(8)));
typedef float f32x4 __attribute__((ext_vector_type(4)));

// B=8, N=1024, C=768, H=12, HD=64, FF=2048, M=8192
// out (f32): src[6291456] | scorenet[8000] | y[8000] | attn[100663296]

__device__ __forceinline__ u16 f2bf(float f) {
  union { float f; unsigned u; } v; v.f = f;
  unsigned r = v.u + 0x7fffu + ((v.u >> 16) & 1u);  // RNE
  return (u16)(r >> 16);
}
__device__ __forceinline__ float bf2f(unsigned u) {
  union { unsigned u; float f; } v; v.u = u << 16; return v.f;
}

__device__ __forceinline__ void async16(const void* g, void* l) {
  __builtin_amdgcn_global_load_lds(
      (const __attribute__((address_space(1))) void*)g,
      (__attribute__((address_space(3))) void*)l, 16, 0, 0);
}

__device__ __forceinline__ f32x4 mfma16(bf16x8 a, bf16x8 b, f32x4 c) {
  return __builtin_amdgcn_mfma_f32_16x16x32_bf16(a, b, c, 0, 0, 0);
}

__device__ __forceinline__ float gelu_exact(float x) {
  return 0.5f * x * (1.0f + erff(x * 0.70710678118654752440f));
}

// ---------------- LayerNorm: f32 [8192,768] -> bf16 (+optional f32) --------
__global__ __launch_bounds__(256) void ln_kernel(
    const float* __restrict__ x, const float* __restrict__ g,
    const float* __restrict__ b, u16* __restrict__ obf,
    float* __restrict__ of) {
  const size_t row = blockIdx.x;
  const float* xr = x + row * 768;
  const int t = threadIdx.x;
  const int w = t >> 6, lane = t & 63;
  float v0 = xr[t], v1 = xr[t + 256], v2 = xr[t + 512];
  float s = v0 + v1 + v2;
  float sq = v0 * v0 + v1 * v1 + v2 * v2;
#pragma unroll
  for (int off = 32; off > 0; off >>= 1) {
    s += __shfl_down(s, off);
    sq += __shfl_down(sq, off);
  }
  __shared__ float ss[4], ssq[4];
  if (lane == 0) { ss[w] = s; ssq[w] = sq; }
  __syncthreads();
  s = ss[0] + ss[1] + ss[2] + ss[3];
  sq = ssq[0] + ssq[1] + ssq[2] + ssq[3];
  const float mean = s * (1.0f / 768.0f);
  const float var = sq * (1.0f / 768.0f) - mean * mean;
  const float rstd = rsqrtf(var + 1e-5f);
  float y0 = (v0 - mean) * rstd * g[t] + b[t];
  float y1 = (v1 - mean) * rstd * g[t + 256] + b[t + 256];
  float y2 = (v2 - mean) * rstd * g[t + 512] + b[t + 512];
  obf[row * 768 + t] = f2bf(y0);
  obf[row * 768 + t + 256] = f2bf(y1);
  obf[row * 768 + t + 512] = f2bf(y2);
  if (of) {
    of[row * 768 + t] = y0;
    of[row * 768 + t + 256] = y1;
    of[row * 768 + t + 512] = y2;
  }
}

// ---- merged: 4 weight transposes (f32 [K][N] -> bf16 [N][K]) + copies -----
__device__ __forceinline__ void transpose_tile(float (*tile)[33],
                                               const float* __restrict__ W,
                                               u16* __restrict__ Wt, int K,
                                               int N, int bx, int by) {
  const int n0 = bx * 32, k0 = by * 32;
  const int tx = threadIdx.x, ty = threadIdx.y;  // (32,8)
  for (int r = ty; r < 32; r += 8)
    tile[r][tx] = W[(size_t)(k0 + r) * N + n0 + tx];
  __syncthreads();
  for (int r = ty; r < 32; r += 8)
    Wt[(size_t)(n0 + r) * K + k0 + tx] = f2bf(tile[tx][r]);
}

__global__ void misc_kernel(const float* __restrict__ qkv_w,
                            const float* __restrict__ proj_w,
                            const float* __restrict__ l1_w,
                            const float* __restrict__ l2_w,
                            u16* __restrict__ qkvwT, u16* __restrict__ projwT,
                            u16* __restrict__ l1wT, u16* __restrict__ l2wT,
                            const float* __restrict__ y,
                            const float* __restrict__ sc,
                            float* __restrict__ out) {
  __shared__ float tile[32][33];
  int bid = blockIdx.x;
  if (bid < 1728) { transpose_tile(tile, qkv_w, qkvwT, 768, 2304, bid % 72, bid / 72); return; }
  bid -= 1728;
  if (bid < 576) { transpose_tile(tile, proj_w, projwT, 768, 768, bid % 24, bid / 24); return; }
  bid -= 576;
  if (bid < 1536) { transpose_tile(tile, l1_w, l1wT, 768, 2048, bid % 64, bid / 64); return; }
  bid -= 1536;
  if (bid < 1536) { transpose_tile(tile, l2_w, l2wT, 2048, 768, bid % 24, bid / 24); return; }
  bid -= 1536;
  const int t = threadIdx.y * 32 + threadIdx.x;
  const int i = bid * 256 + t;
  if (i < 8000) {
    out[6291456 + i] = sc[i];
    out[6299456 + i] = y[i];
  }
}

// ------------- V transpose: qkv bf16 -> vt[bh][d][n] ------------------------
__global__ void vt_kernel(const u16* __restrict__ qkv, u16* __restrict__ vt) {
  // grid (32, 2, 96), block (32,8)
  const int bh = blockIdx.z, b = bh / 12, h = bh % 12;
  const int n0 = blockIdx.x * 32, d0 = blockIdx.y * 32;
  __shared__ u16 tile[32][33];
  const u16* Vp = qkv + (size_t)b * 1024 * 2304 + 1536 + h * 64;
  const int tx = threadIdx.x, ty = threadIdx.y;
  for (int r = ty; r < 32; r += 8)
    tile[r][tx] = Vp[(size_t)(n0 + r) * 2304 + d0 + tx];
  __syncthreads();
  u16* Op = vt + (size_t)bh * 64 * 1024;
  for (int r = ty; r < 32; r += 8)
    Op[(size_t)(d0 + r) * 1024 + n0 + tx] = tile[tx][r];
}

// ------------- templated bf16 MFMA GEMM --------------------------------------
// C[M,N] = A[M,K] @ Bt[N,K]^T ; wave grid (4/GN)xGN, per-wave WMxWN m16/n16
template <int BM, int BN, int GN, int WM, int WN>
__global__ __launch_bounds__(256) void gemm_kernel(
    const u16* __restrict__ A, int lda, const u16* __restrict__ Bt, int ldb,
    const float* __restrict__ bias, const float* __restrict__ res,
    float* __restrict__ outF, u16* __restrict__ outB, int ldc, int K,
    int act) {
  __shared__ u16 As[BM * 32];
  __shared__ u16 Bs[BN * 32];
  const int tid = threadIdx.x;
  const int w = tid >> 6, lane = tid & 63;
  const size_t mBase = (size_t)blockIdx.y * BM;
  const size_t nBase = (size_t)blockIdx.x * BN;
  const int rq = lane >> 2;       // row within 16-row chunk
  const int k8 = (lane & 3) * 8;  // k-offset of this lane's 16B
  const int wmBase = (w / GN) * (WM * 16);
  const int wnBase = (w % GN) * (WN * 16);
  const int tm = lane & 15, kq = lane >> 4;
  const f32x4 zero = {0.f, 0.f, 0.f, 0.f};
  f32x4 acc[WM][WN];
#pragma unroll
  for (int i = 0; i < WM; i++)
#pragma unroll
    for (int j = 0; j < WN; j++) acc[i][j] = zero;

  for (int kt = 0; kt < K; kt += 32) {
    __syncthreads();
#pragma unroll
    for (int c = w; c < BM / 16; c += 4)
      async16(A + (mBase + c * 16 + rq) * lda + kt + k8, &As[c * 16 * 32]);
#pragma unroll
    for (int c = w; c < BN / 16; c += 4)
      async16(Bt + (nBase + c * 16 + rq) * ldb + kt + k8, &Bs[c * 16 * 32]);
    __syncthreads();
    bf16x8 af[WM], bfv[WN];
#pragma unroll
    for (int i = 0; i < WM; i++)
      af[i] = *(const bf16x8*)&As[(wmBase + i * 16 + tm) * 32 + kq * 8];
#pragma unroll
    for (int j = 0; j < WN; j++)
      bfv[j] = *(const bf16x8*)&Bs[(wnBase + j * 16 + tm) * 32 + kq * 8];
#pragma unroll
    for (int i = 0; i < WM; i++)
#pragma unroll
      for (int j = 0; j < WN; j++) acc[i][j] = mfma16(af[i], bfv[j], acc[i][j]);
  }

#pragma unroll
  for (int i = 0; i < WM; i++) {
    const size_t row0 = mBase + wmBase + i * 16 + kq * 4;
#pragma unroll
    for (int j = 0; j < WN; j++) {
      const size_t col = nBase + wnBase + j * 16 + tm;
      const float bv = bias ? bias[col] : 0.0f;
#pragma unroll
      for (int r = 0; r < 4; r++) {
        const size_t rr = row0 + r;
        float v = acc[i][j][r] + bv;
        if (act) v = gelu_exact(v);
        if (res) v += res[rr * ldc + col];
        if (outF) outF[rr * ldc + col] = v;
        if (outB) outB[rr * ldc + col] = f2bf(v);
      }
    }
  }
}

// ------------- fused flash attention, two-phase recompute -------------------
// block = (32 Q-rows, bh). Phase 1: S -> exp -> row sums only (registers).
// Phase 2: recompute S, p = exp(s)*rinv, write attn f32 once, P->LDS (bf16,
// swizzled), AV MFMA. All LDS tiles XOR-swizzled (<=2-way bank aliasing).
__global__ __launch_bounds__(256, 3) void flash_kernel(
    const u16* __restrict__ qkv, const u16* __restrict__ vt,
    float* __restrict__ attn, u16* __restrict__ aout) {
  __shared__ u16 Qs[32 * 64];       // 4 KB
  __shared__ u16 KV[2 * 128 * 64];  // 32 KB (ph1: K 256x64; ph2: K|V 128x64)
  __shared__ u16 Ps[32 * 128];      // 8 KB
  __shared__ float psum[4][32];
  __shared__ float rinv[32];
  const int tid = threadIdx.x;
  const int w = tid >> 6, lane = tid & 63;
  const int tm = lane & 15, kq = lane >> 4;
  const int bh = blockIdx.y, b = bh / 12, h = bh % 12;
  const size_t m0 = (size_t)blockIdx.x * 32;
  const u16* Qp = qkv + (size_t)b * 1024 * 2304 + h * 64;
  const u16* Kp = Qp + 768;
  const u16* Vp = vt + (size_t)bh * 64 * 1024;
  float* Ab = attn + ((size_t)bh * 1024 + m0) * 1024;

  // stage Q strip (32x64), swizzled 16B chunks
  {
    const int r = tid >> 3, c = tid & 7;
    *(uint4*)&Qs[r * 64 + ((c ^ (r & 7)) * 8)] =
        *(const uint4*)(Qp + (m0 + r) * 2304 + c * 8);
  }
  __syncthreads();
  // A-fragments (Q) are fixed for the whole kernel
  bf16x8 aq[2][2];
#pragma unroll
  for (int i = 0; i < 2; i++)
#pragma unroll
    for (int k2 = 0; k2 < 2; k2++) {
      const int m = i * 16 + tm;
      aq[i][k2] =
          *(const bf16x8*)&Qs[m * 64 + (((k2 * 4 + kq) ^ (m & 7)) * 8)];
    }

  // ---- phase 1: row sums, K-chunks of 256 ----
  f32x4 rs[2] = {{0.f, 0.f, 0.f, 0.f}, {0.f, 0.f, 0.f, 0.f}};
  for (int cc = 0; cc < 4; ++cc) {
    const int nc = cc * 256;
    __syncthreads();
#pragma unroll
    for (int u = 0; u < 8; ++u) {
      const int idx = u * 256 + tid;
      const int r = idx >> 3, c = idx & 7;
      *(uint4*)&KV[r * 64 + ((c ^ (r & 7)) * 8)] =
          *(const uint4*)(Kp + (size_t)(nc + r) * 2304 + c * 8);
    }
    __syncthreads();
#pragma unroll
    for (int jj = 0; jj < 4; ++jj) {
      const int n = (w * 4 + jj) * 16 + tm;
      bf16x8 bk[2];
#pragma unroll
      for (int k2 = 0; k2 < 2; k2++)
        bk[k2] =
            *(const bf16x8*)&KV[n * 64 + (((k2 * 4 + kq) ^ (n & 7)) * 8)];
#pragma unroll
      for (int i = 0; i < 2; i++) {
        f32x4 s = {0.f, 0.f, 0.f, 0.f};
        s = mfma16(aq[i][0], bk[0], s);
        s = mfma16(aq[i][1], bk[1], s);
#pragma unroll
        for (int r = 0; r < 4; r++) rs[i][r] += __expf(s[r] * 0.125f);
      }
    }
  }
  // reduce row sums across the 16 col-lanes, combine waves via LDS
#pragma unroll
  for (int i = 0; i < 2; i++)
#pragma unroll
    for (int r = 0; r < 4; r++) {
      float v = rs[i][r];
      v += __shfl_xor(v, 1); v += __shfl_xor(v, 2);
      v += __shfl_xor(v, 4); v += __shfl_xor(v, 8);
      if (tm == 0) psum[w][i * 16 + kq * 4 + r] = v;
    }
  __syncthreads();
  if (tid < 32)
    rinv[tid] =
        1.0f / (psum[0][tid] + psum[1][tid] + psum[2][tid] + psum[3][tid]);

  // ---- phase 2: recompute, write attn, AV ----
  const f32x4 zero = {0.f, 0.f, 0.f, 0.f};
  f32x4 oacc[2] = {zero, zero};
  const int mi = w & 1, dp = w >> 1;
  for (int cc = 0; cc < 8; ++cc) {
    const int nc = cc * 128;
    __syncthreads();  // guards KV+Ps reuse (and rinv on first iter)
#pragma unroll
    for (int u = 0; u < 4; ++u) {
      const int idx = u * 256 + tid;
      const int r = idx >> 3, c = idx & 7;
      *(uint4*)&KV[r * 64 + ((c ^ (r & 7)) * 8)] =
          *(const uint4*)(Kp + (size_t)(nc + r) * 2304 + c * 8);
    }
#pragma unroll
    for (int u = 0; u < 4; ++u) {
      const int idx = u * 256 + tid;
      const int d = idx >> 4, c = idx & 15;
      *(uint4*)&KV[8192 + d * 128 + ((c ^ (d & 15)) * 8)] =
          *(const uint4*)(Vp + (size_t)d * 1024 + nc + c * 8);
    }
    __syncthreads();
    // S recompute for this wave's 32 cols; normalize; write attn + Ps
#pragma unroll
    for (int jj = 0; jj < 2; ++jj) {
      const int nb = w * 2 + jj;
      const int n = nb * 16 + tm;
      bf16x8 bk[2];
#pragma unroll
      for (int k2 = 0; k2 < 2; k2++)
        bk[k2] =
            *(const bf16x8*)&KV[n * 64 + (((k2 * 4 + kq) ^ (n & 7)) * 8)];
#pragma unroll
      for (int i = 0; i < 2; i++) {
        f32x4 s = {0.f, 0.f, 0.f, 0.f};
        s = mfma16(aq[i][0], bk[0], s);
        s = mfma16(aq[i][1], bk[1], s);
        const int row = i * 16 + kq * 4;
#pragma unroll
        for (int r = 0; r < 4; r++) {
          const float p = __expf(s[r] * 0.125f) * rinv[row + r];
          Ab[(size_t)(row + r) * 1024 + nc + nb * 16 + tm] = p;
          const int pr = row + r, pn = nb * 16 + tm;
          Ps[pr * 128 + (((pn >> 3) ^ (pr & 7)) * 8) + (pn & 7)] = f2bf(p);
        }
      }
    }
    __syncthreads();
    // AV: wave owns (m-block mi, d-blocks 2*dp, 2*dp+1)
#pragma unroll
    for (int k2 = 0; k2 < 4; ++k2) {
      const int m = mi * 16 + tm;
      const bf16x8 ap =
          *(const bf16x8*)&Ps[m * 128 + (((k2 * 4 + kq) ^ (m & 7)) * 8)];
#pragma unroll
      for (int jd = 0; jd < 2; ++jd) {
        const int d = dp * 32 + jd * 16 + tm;
        const bf16x8 bv = *(const bf16x8*)&KV[8192 + d * 128 +
                                              (((k2 * 4 + kq) ^ (d & 15)) * 8)];
        oacc[jd] = mfma16(ap, bv, oacc[jd]);
      }
    }
  }
  // epilogue: O already normalized
#pragma unroll
  for (int jd = 0; jd < 2; ++jd)
#pragma unroll
    for (int r = 0; r < 4; ++r) {
      const size_t gm = (size_t)b * 1024 + m0 + mi * 16 + kq * 4 + r;
      aout[gm * 768 + h * 64 + dp * 32 + jd * 16 + tm] = f2bf(oacc[jd][r]);
    }
}

extern "C" void kernel_launch(void* const* d_in, const int* in_sizes, int n_in,
                              void* d_out, int out_size, void* d_ws,
                              size_t ws_size, hipStream_t stream) {
  const float* src    = (const float*)d_in[0];
  const float* yin    = (const float*)d_in[1];
  const float* scin   = (const float*)d_in[2];
  const float* pre_g  = (const float*)d_in[3];
  const float* pre_b  = (const float*)d_in[4];
  const float* qkv_w  = (const float*)d_in[5];
  const float* proj_w = (const float*)d_in[6];
  const float* proj_b = (const float*)d_in[7];
  const float* n1_g   = (const float*)d_in[8];
  const float* n1_b   = (const float*)d_in[9];
  const float* l1_w   = (const float*)d_in[10];
  const float* l1_b   = (const float*)d_in[11];
  const float* l2_w   = (const float*)d_in[12];
  const float* l2_b   = (const float*)d_in[13];
  float* outp = (float*)d_out;
  float* attn = outp + 6307456;

  char* ws = (char*)d_ws;
  u16* qkvwT  = (u16*)(ws + 0ull);          // 2304x768
  u16* projwT = (u16*)(ws + 3538944ull);    // 768x768
  u16* l1wT   = (u16*)(ws + 4718592ull);    // 2048x768
  u16* l2wT   = (u16*)(ws + 7864320ull);    // 768x2048
  const size_t P0 = 11010048ull;
  u16* xn   = (u16*)(ws + P0);                 // 8192x768 bf16
  u16* qkv  = (u16*)(ws + P0 + 12582912ull);   // 8192x2304 bf16
  u16* vt   = (u16*)(ws + P0 + 50331648ull);   // 96x64x1024 bf16
  u16* aout = (u16*)(ws + P0 + 62914560ull);   // 8192x768 bf16
  float* src2 = (float*)(ws + P0);                // 8192x768 f32
  u16*  snb   = (u16*)(ws + P0 + 25165824ull);    // 8192x768 bf16
  u16*  hbuf  = (u16*)(ws + P0 + 37748736ull);    // 8192x2048 bf16
  float* snf  = (float*)(ws + P0 + 71303168ull);  // 8192x768 f32

  dim3 tb(32, 8);
  misc_kernel<<<5439, tb, 0, stream>>>(qkv_w, proj_w, l1_w, l2_w, qkvwT,
                                       projwT, l1wT, l2wT, yin, scin, outp);
  ln_kernel<<<8192, 256, 0, stream>>>(src, pre_g, pre_b, xn, nullptr);
  // QKV: [8192,768]@[768,2304] -> bf16
  gemm_kernel<128, 128, 2, 4, 4><<<dim3(18, 64), 256, 0, stream>>>(
      xn, 768, qkvwT, 768, nullptr, nullptr, nullptr, qkv, 2304, 768, 0);
  vt_kernel<<<dim3(32, 2, 96), tb, 0, stream>>>(qkv, vt);
  // fused scores+softmax+AV (writes attn f32 once, aout bf16)
  flash_kernel<<<dim3(32, 96), 256, 0, stream>>>(qkv, vt, attn, aout);
  // proj + residual(src) -> src2 f32
  gemm_kernel<64, 128, 4, 4, 2><<<dim3(6, 128), 256, 0, stream>>>(
      aout, 768, projwT, 768, proj_b, src, src2, nullptr, 768, 768, 0);
  ln_kernel<<<8192, 256, 0, stream>>>(src2, n1_g, n1_b, snb, snf);
  // FFN1 + exact GELU -> bf16
  gemm_kernel<128, 128, 2, 4, 4><<<dim3(16, 64), 256, 0, stream>>>(
      snb, 768, l1wT, 768, l1_b, nullptr, nullptr, hbuf, 2048, 768, 1);
  // FFN2 + residual(src_n) -> out
  gemm_kernel<64, 128, 4, 4, 2><<<dim3(6, 128), 256, 0, stream>>>(
      hbuf, 2048, l2wT, 2048, l2_b, snf, outp, nullptr, 768, 2048, 0);
}